// Round 1
// baseline (259.878 us; speedup 1.0000x reference)
//
#include <hip/hip_runtime.h>
#include <math.h>

#define Bb 4
#define Cc 64
#define Hh 96
#define Ww 96
#define Oo 128
#define HW (Hh * Ww)      // 9216
#define NPOS (Bb * HW)    // 36864

// ---------------------------------------------------------------------------
// Kernel 1: offset/modulator 3x3 conv (64 -> 27 channels), pad=1, stride=1.
// Grid: 144 position-blocks x 4 channel-groups (7,7,7,6). Block 256 threads,
// one thread per output pixel, 7 channel accumulators.
// Writes offm[b][ch][h][w]: ch 0..17 = offset(+bias), ch 18..26 = 2*sigmoid.
// ---------------------------------------------------------------------------
__global__ __launch_bounds__(256) void k_offmask(
    const float* __restrict__ x, const float* __restrict__ ow,
    const float* __restrict__ ob, const float* __restrict__ mw,
    const float* __restrict__ mb, float* __restrict__ offm)
{
    const int grp = blockIdx.x & 3;
    const int posblk = blockIdx.x >> 2;
    const int t = threadIdx.x;
    const int pos = posblk * 256 + t;
    const int b = pos / HW;
    const int p = pos - b * HW;
    const int ho = p / Ww;
    const int wo = p - ho * Ww;
    const int oc0 = grp * 7;

    __shared__ float wsm[7 * Cc * 9];   // [i][c][kk], 16 KB
    for (int i = t; i < 7 * Cc * 9; i += 256) {
        int oc = oc0 + i / (Cc * 9);
        int r = i % (Cc * 9);
        float v = 0.f;
        if (oc < 18)      v = ow[oc * Cc * 9 + r];
        else if (oc < 27) v = mw[(oc - 18) * Cc * 9 + r];
        wsm[i] = v;
    }
    __syncthreads();

    float acc[7];
#pragma unroll
    for (int i = 0; i < 7; ++i) acc[i] = 0.f;

    const float* xb = x + (size_t)b * Cc * HW;
    for (int c = 0; c < Cc; ++c) {
        float xv[9];
#pragma unroll
        for (int ki = 0; ki < 3; ++ki) {
#pragma unroll
            for (int kj = 0; kj < 3; ++kj) {
                int h = ho - 1 + ki;
                int w = wo - 1 + kj;
                bool ok = ((unsigned)h < (unsigned)Hh) & ((unsigned)w < (unsigned)Ww);
                xv[ki * 3 + kj] = ok ? xb[c * HW + h * Ww + w] : 0.f;
            }
        }
#pragma unroll
        for (int i = 0; i < 7; ++i) {
            float a = acc[i];
#pragma unroll
            for (int kk = 0; kk < 9; ++kk)
                a = fmaf(xv[kk], wsm[i * (Cc * 9) + c * 9 + kk], a);
            acc[i] = a;
        }
    }

#pragma unroll
    for (int i = 0; i < 7; ++i) {
        int oc = oc0 + i;
        if (oc < 18) {
            offm[((size_t)b * 27 + oc) * HW + p] = acc[i] + ob[oc];
        } else if (oc < 27) {
            float v = acc[i] + mb[oc - 18];
            offm[((size_t)b * 27 + oc) * HW + p] = 2.f / (1.f + expf(-v));
        }
    }
}

// ---------------------------------------------------------------------------
// Kernel 1b: transpose deform weights (O,C,3,3) -> wT[k][c][oc]
// ---------------------------------------------------------------------------
__global__ __launch_bounds__(256) void k_wT(const float* __restrict__ w,
                                            float* __restrict__ wT)
{
    int i = blockIdx.x * 256 + threadIdx.x;     // i < 9*64*128 = 73728
    int oc = i & 127;
    int c = (i >> 7) & 63;
    int k = i >> 13;
    wT[i] = w[(oc * Cc + c) * 9 + k];
}

// ---------------------------------------------------------------------------
// Kernel 2: deformable conv. Block = 64 spatial positions x 128 out-channels.
// Per k: bilinear params -> LDS, weight slice -> LDS, sampled v[c][pos] -> LDS,
// then 8x4 register-blocked outer product over c=64.
// ---------------------------------------------------------------------------
__global__ __launch_bounds__(256) void k_deform(
    const float* __restrict__ x, const float* __restrict__ offm,
    const float* __restrict__ wT, float* __restrict__ out)
{
    __shared__ float v_s[Cc * 64];      // [c][pos], 16 KB
    __shared__ float w_s[Cc * Oo];      // [c][oc], 32 KB
    __shared__ float s_w[4][64];        // bilinear corner weights (mask folded)
    __shared__ int   s_i[4][64];        // clamped flat indices

    const int t = threadIdx.x;
    const int blk = blockIdx.x;         // 576 = 4 * 144
    const int b = blk / 144;
    const int ptile = (blk - b * 144) * 64;
    const int to = t & 15;              // oc = to*8 + i
    const int tp = t >> 4;              // pos = tp*4 + j  (tp in 0..15)
    const int spos = t & 63;            // sampling: position
    const int scg = t >> 6;             // sampling: c group (16 c each)

    float acc[8][4];
#pragma unroll
    for (int i = 0; i < 8; ++i)
#pragma unroll
        for (int j = 0; j < 4; ++j) acc[i][j] = 0.f;

    const float* xb = x + (size_t)b * Cc * HW;
    const float* offb = offm + (size_t)b * 27 * HW;

    for (int k = 0; k < 9; ++k) {
        __syncthreads();   // previous compute done; v_s/w_s/s_w free
        if (t < 64) {
            int p = ptile + t;
            int ho = p / Ww;
            int wo = p - ho * Ww;
            float dy = offb[(2 * k) * HW + p];
            float dx = offb[(2 * k + 1) * HW + p];
            float m  = offb[(18 + k) * HW + p];
            float py = (float)(ho - 1 + k / 3) + dy;
            float px = (float)(wo - 1 + (k % 3)) + dx;
            float fy = floorf(py), fx = floorf(px);
            float ly = py - fy, lx = px - fx;
            int y0 = (int)fy, x0 = (int)fx;
            int y1 = y0 + 1, x1 = x0 + 1;
            float v00 = ((unsigned)y0 < (unsigned)Hh && (unsigned)x0 < (unsigned)Ww) ? 1.f : 0.f;
            float v01 = ((unsigned)y0 < (unsigned)Hh && (unsigned)x1 < (unsigned)Ww) ? 1.f : 0.f;
            float v10 = ((unsigned)y1 < (unsigned)Hh && (unsigned)x0 < (unsigned)Ww) ? 1.f : 0.f;
            float v11 = ((unsigned)y1 < (unsigned)Hh && (unsigned)x1 < (unsigned)Ww) ? 1.f : 0.f;
            int cy0 = min(max(y0, 0), Hh - 1), cy1 = min(max(y1, 0), Hh - 1);
            int cx0 = min(max(x0, 0), Ww - 1), cx1 = min(max(x1, 0), Ww - 1);
            s_w[0][t] = (1.f - ly) * (1.f - lx) * m * v00;
            s_w[1][t] = (1.f - ly) * lx * m * v01;
            s_w[2][t] = ly * (1.f - lx) * m * v10;
            s_w[3][t] = ly * lx * m * v11;
            s_i[0][t] = cy0 * Ww + cx0;
            s_i[1][t] = cy0 * Ww + cx1;
            s_i[2][t] = cy1 * Ww + cx0;
            s_i[3][t] = cy1 * Ww + cx1;
        }
        // cooperative load of weight slice for this k: [c][oc] contiguous
        {
            const float* wk = wT + (size_t)k * Cc * Oo;
            for (int i = t; i < Cc * Oo; i += 256) w_s[i] = wk[i];
        }
        __syncthreads();   // params + weights visible

        // sampling: each thread does 16 channels at one position
        {
            float w0 = s_w[0][spos], w1 = s_w[1][spos];
            float w2 = s_w[2][spos], w3 = s_w[3][spos];
            int i0 = s_i[0][spos], i1 = s_i[1][spos];
            int i2 = s_i[2][spos], i3 = s_i[3][spos];
            const float* xc = xb + (size_t)scg * 16 * HW;
#pragma unroll 4
            for (int cc = 0; cc < 16; ++cc) {
                const float* xp = xc + cc * HW;
                float v = w0 * xp[i0] + w1 * xp[i1] + w2 * xp[i2] + w3 * xp[i3];
                v_s[(scg * 16 + cc) * 64 + spos] = v;
            }
        }
        __syncthreads();   // v_s ready

        // compute: acc[i][j] += w[c][to*8+i] * v[c][tp*4+j]
#pragma unroll 4
        for (int c = 0; c < Cc; ++c) {
            const float4 w0 = *(const float4*)&w_s[c * Oo + to * 8];
            const float4 w1 = *(const float4*)&w_s[c * Oo + to * 8 + 4];
            const float4 vv = *(const float4*)&v_s[c * 64 + tp * 4];
            float wr[8] = {w0.x, w0.y, w0.z, w0.w, w1.x, w1.y, w1.z, w1.w};
            float vr[4] = {vv.x, vv.y, vv.z, vv.w};
#pragma unroll
            for (int i = 0; i < 8; ++i)
#pragma unroll
                for (int j = 0; j < 4; ++j)
                    acc[i][j] = fmaf(wr[i], vr[j], acc[i][j]);
        }
    }

    // epilogue: out[b][oc][pos]
#pragma unroll
    for (int i = 0; i < 8; ++i) {
        int oc = to * 8 + i;
        float4 o4 = make_float4(acc[i][0], acc[i][1], acc[i][2], acc[i][3]);
        *(float4*)&out[((size_t)b * Oo + oc) * HW + ptile + tp * 4] = o4;
    }
}

extern "C" void kernel_launch(void* const* d_in, const int* in_sizes, int n_in,
                              void* d_out, int out_size, void* d_ws, size_t ws_size,
                              hipStream_t stream) {
    const float* x  = (const float*)d_in[0];
    const float* ow = (const float*)d_in[1];
    const float* ob = (const float*)d_in[2];
    const float* mw = (const float*)d_in[3];
    const float* mb = (const float*)d_in[4];
    const float* dw = (const float*)d_in[5];
    float* out = (float*)d_out;

    float* offm = (float*)d_ws;                    // 4*27*9216 = 995328 floats
    float* wT   = offm + (size_t)Bb * 27 * HW;     // 73728 floats

    hipLaunchKernelGGL(k_offmask, dim3(576), dim3(256), 0, stream,
                       x, ow, ob, mw, mb, offm);
    hipLaunchKernelGGL(k_wT, dim3(288), dim3(256), 0, stream, dw, wT);
    hipLaunchKernelGGL(k_deform, dim3(576), dim3(256), 0, stream,
                       x, offm, wT, out);
}

// Round 2
// 183.832 us; speedup vs baseline: 1.4137x; 1.4137x over previous
//
#include <hip/hip_runtime.h>
#include <math.h>

#define Bc 4
#define Cc 64
#define Hh 96
#define Ww 96
#define Oo 128
#define HW 9216          // Hh*Ww
#define PT 32            // positions per block
#define NPB 288          // HW/PT position-tiles per batch image
#define LDW 72           // padded K stride (bf16 elems): 144 B, 16B-aligned rows

typedef __attribute__((ext_vector_type(8))) short bf16x8;
typedef __attribute__((ext_vector_type(4))) float f32x4;

__device__ inline unsigned short f2bf(float f) {
    unsigned u = __builtin_bit_cast(unsigned, f);
    return (unsigned short)((u + 0x7FFF + ((u >> 16) & 1)) >> 16);  // RNE
}

// ---------------------------------------------------------------------------
// Prep: transpose + bf16-cast weights.
//   wTm[k][oc][c]  (9 x 128 x 64)  from dw (O,C,3,3)
//   wT27[k][ch][c] (9 x 32 x 64)   ch 0..17 = offset conv w, 18..26 = mod w, rest 0
// ---------------------------------------------------------------------------
__global__ __launch_bounds__(256) void k_prep(
    const float* __restrict__ dw, const float* __restrict__ ow,
    const float* __restrict__ mw, unsigned short* __restrict__ wTm,
    unsigned short* __restrict__ wT27)
{
    int i = blockIdx.x * 256 + threadIdx.x;
    if (i < 9 * 128 * 64) {
        int c = i & 63, oc = (i >> 6) & 127, k = i >> 13;
        wTm[i] = f2bf(dw[(oc * 64 + c) * 9 + k]);
    }
    int j = i - 9 * 128 * 64;
    if (j >= 0 && j < 9 * 32 * 64) {
        int c = j & 63, ch = (j >> 6) & 31, k = j >> 11;
        float v = 0.f;
        if (ch < 18)      v = ow[(ch * 64 + c) * 9 + k];
        else if (ch < 27) v = mw[((ch - 18) * 64 + c) * 9 + k];
        wT27[j] = f2bf(v);
    }
}

// ---------------------------------------------------------------------------
// Fused kernel: offset/mask conv (MFMA) -> sigmoid -> bilinear sampling ->
// main deform GEMM (MFMA). One block = 32 positions x all 128 out-channels.
// mfma_f32_16x16x32_bf16 layouts:
//   A[m = lane&15][k = (lane>>4)*8 + j]   (8 bf16 contiguous in k)
//   B[k = (lane>>4)*8 + j][n = lane&15]
//   D: col(n) = lane&15, row(m) = (lane>>4)*4 + reg
// Both A and B frags load 8 contiguous bf16 from a [row][k]-major LDS array.
// ---------------------------------------------------------------------------
__global__ __launch_bounds__(256, 4) void k_fused(
    const float* __restrict__ x, const float* __restrict__ ob,
    const float* __restrict__ mb, const unsigned short* __restrict__ wTm,
    const unsigned short* __restrict__ wT27, float* __restrict__ out)
{
    __shared__ short w_lds[128 * LDW];   // phase1: w27 rows 0..31; phase3: w_main
    __shared__ short v_lds[PT * LDW];    // phase1: shifted x tile; phase3: sampled v
    __shared__ float offm_s[27 * 33];    // [ch][pos], stride 33
    __shared__ float s_w[4][PT];
    __shared__ int   s_i[4][PT];

    const int t = threadIdx.x;
    const int bq = blockIdx.x;                 // 0..1151
    const int bb = bq / NPB;
    const int ptile = (bq - bb * NPB) * PT;
    const int wv = t >> 6;
    const int l = t & 63;
    const int lr = l & 15;
    const int quad = l >> 4;

    const float* xb = x + (size_t)bb * Cc * HW;

    // ======== phase 1: 3x3 conv 64 -> 27 via MFMA (K = 9 taps x 64c) ========
    f32x4 acc_o = {0.f, 0.f, 0.f, 0.f};
    const int mt1 = wv & 1;                    // pos half-tile
    const int nt1 = wv >> 1;                   // ch half-tile
    for (int k = 0; k < 9; ++k) {
        const int di = k / 3 - 1, dj = k % 3 - 1;
        // stage shifted x tile: xs[pos][c] into v_lds (zero outside image)
        for (int i = t; i < PT * Cc; i += 256) {
            int c = i >> 5, pl = i & 31;
            int p = ptile + pl;
            int ho = p / Ww, wo = p - ho * Ww;
            int h = ho + di, w2 = wo + dj;
            float v = 0.f;
            if ((unsigned)h < (unsigned)Hh && (unsigned)w2 < (unsigned)Ww)
                v = xb[c * HW + h * Ww + w2];
            v_lds[pl * LDW + c] = (short)f2bf(v);
        }
        // stage w27[ch][c] for this tap
        for (int i = t; i < 32 * Cc; i += 256) {
            int ch = i >> 6, c = i & 63;
            w_lds[ch * LDW + c] = (short)wT27[k * 2048 + i];
        }
        __syncthreads();
#pragma unroll
        for (int ks = 0; ks < 64; ks += 32) {
            bf16x8 a = *(const bf16x8*)&v_lds[(mt1 * 16 + lr) * LDW + ks + quad * 8];
            bf16x8 b = *(const bf16x8*)&w_lds[(nt1 * 16 + lr) * LDW + ks + quad * 8];
            acc_o = __builtin_amdgcn_mfma_f32_16x16x32_bf16(a, b, acc_o, 0, 0, 0);
        }
        __syncthreads();
    }
    // write conv result to offm_s:  m=pos, n=ch
    {
        int ch = nt1 * 16 + lr;
        if (ch < 27) {
#pragma unroll
            for (int r = 0; r < 4; ++r) {
                int pos = mt1 * 16 + quad * 4 + r;
                offm_s[ch * 33 + pos] = acc_o[r];
            }
        }
    }
    __syncthreads();
    // ======== phase 2: bias + 2*sigmoid ========
    for (int i = t; i < 27 * PT; i += 256) {
        int ch = i >> 5, pos = i & 31;
        float v = offm_s[ch * 33 + pos];
        if (ch < 18) v += ob[ch];
        else         v = 2.f / (1.f + expf(-(v + mb[ch - 18])));
        offm_s[ch * 33 + pos] = v;
    }
    __syncthreads();

    // ======== phase 3: sampling + main GEMM ========
    f32x4 accm[2][2];
#pragma unroll
    for (int mi = 0; mi < 2; ++mi)
#pragma unroll
        for (int ni = 0; ni < 2; ++ni)
            accm[mi][ni] = (f32x4){0.f, 0.f, 0.f, 0.f};

    for (int k = 0; k < 9; ++k) {
        // (a) bilinear params for the 32 positions
        if (t < PT) {
            int p = ptile + t;
            int ho = p / Ww, wo = p - ho * Ww;
            float dy = offm_s[(2 * k) * 33 + t];
            float dx = offm_s[(2 * k + 1) * 33 + t];
            float mm = offm_s[(18 + k) * 33 + t];
            float py = (float)(ho - 1 + k / 3) + dy;
            float px = (float)(wo - 1 + (k % 3)) + dx;
            float fy = floorf(py), fx = floorf(px);
            float ly = py - fy, lx = px - fx;
            int y0 = (int)fy, x0 = (int)fx;
            int y1 = y0 + 1, x1 = x0 + 1;
            float v00 = ((unsigned)y0 < (unsigned)Hh && (unsigned)x0 < (unsigned)Ww) ? 1.f : 0.f;
            float v01 = ((unsigned)y0 < (unsigned)Hh && (unsigned)x1 < (unsigned)Ww) ? 1.f : 0.f;
            float v10 = ((unsigned)y1 < (unsigned)Hh && (unsigned)x0 < (unsigned)Ww) ? 1.f : 0.f;
            float v11 = ((unsigned)y1 < (unsigned)Hh && (unsigned)x1 < (unsigned)Ww) ? 1.f : 0.f;
            int cy0 = min(max(y0, 0), Hh - 1), cy1 = min(max(y1, 0), Hh - 1);
            int cx0 = min(max(x0, 0), Ww - 1), cx1 = min(max(x1, 0), Ww - 1);
            s_w[0][t] = (1.f - ly) * (1.f - lx) * mm * v00;
            s_w[1][t] = (1.f - ly) * lx * mm * v01;
            s_w[2][t] = ly * (1.f - lx) * mm * v10;
            s_w[3][t] = ly * lx * mm * v11;
            s_i[0][t] = cy0 * Ww + cx0;
            s_i[1][t] = cy0 * Ww + cx1;
            s_i[2][t] = cy1 * Ww + cx0;
            s_i[3][t] = cy1 * Ww + cx1;
        }
        // (b) stage main weights w[oc][c] for this tap (b64 chunks)
        {
            const ushort4* src = (const ushort4*)(wTm + k * 8192);
#pragma unroll
            for (int it = 0; it < 8; ++it) {
                int idx4 = t + it * 256;           // 0..2047
                ushort4 d4 = src[idx4];
                int g = idx4 * 4;
                int oc = g >> 6, c = g & 63;
                *(ushort4*)&w_lds[oc * LDW + c] = d4;
            }
        }
        __syncthreads();
        // (c) sample: thread -> (pos = t&31, 8 channels), write bf16x4 chunks
        {
            int pos = t & 31, cg = t >> 5;
            float w0 = s_w[0][pos], w1 = s_w[1][pos];
            float w2 = s_w[2][pos], w3 = s_w[3][pos];
            int i0 = s_i[0][pos], i1 = s_i[1][pos];
            int i2 = s_i[2][pos], i3 = s_i[3][pos];
#pragma unroll
            for (int q = 0; q < 2; ++q) {
                int c0 = cg * 8 + q * 4;
                unsigned short tmp[4];
#pragma unroll
                for (int cc2 = 0; cc2 < 4; ++cc2) {
                    const float* xp = xb + (c0 + cc2) * HW;
                    float v = w0 * xp[i0] + w1 * xp[i1] + w2 * xp[i2] + w3 * xp[i3];
                    tmp[cc2] = f2bf(v);
                }
                ushort4 pk = make_ushort4(tmp[0], tmp[1], tmp[2], tmp[3]);
                *(ushort4*)&v_lds[pos * LDW + c0] = pk;
            }
        }
        __syncthreads();
        // (d) GEMM: D[oc][pos] += w[oc][c] * v[pos][c]
#pragma unroll
        for (int ks = 0; ks < 64; ks += 32) {
            bf16x8 a0 = *(const bf16x8*)&w_lds[(wv * 32 + lr) * LDW + ks + quad * 8];
            bf16x8 a1 = *(const bf16x8*)&w_lds[(wv * 32 + 16 + lr) * LDW + ks + quad * 8];
            bf16x8 b0 = *(const bf16x8*)&v_lds[lr * LDW + ks + quad * 8];
            bf16x8 b1 = *(const bf16x8*)&v_lds[(16 + lr) * LDW + ks + quad * 8];
            accm[0][0] = __builtin_amdgcn_mfma_f32_16x16x32_bf16(a0, b0, accm[0][0], 0, 0, 0);
            accm[0][1] = __builtin_amdgcn_mfma_f32_16x16x32_bf16(a0, b1, accm[0][1], 0, 0, 0);
            accm[1][0] = __builtin_amdgcn_mfma_f32_16x16x32_bf16(a1, b0, accm[1][0], 0, 0, 0);
            accm[1][1] = __builtin_amdgcn_mfma_f32_16x16x32_bf16(a1, b1, accm[1][1], 0, 0, 0);
        }
        __syncthreads();
    }

    // epilogue: out[b][oc][pos];  m=oc (row), n=pos (col)
    float* outp = out + (size_t)bb * Oo * HW + ptile;
#pragma unroll
    for (int mi = 0; mi < 2; ++mi) {
#pragma unroll
        for (int r = 0; r < 4; ++r) {
            int oc = (2 * wv + mi) * 16 + quad * 4 + r;
#pragma unroll
            for (int ni = 0; ni < 2; ++ni) {
                outp[(size_t)oc * HW + ni * 16 + lr] = accm[mi][ni][r];
            }
        }
    }
}

extern "C" void kernel_launch(void* const* d_in, const int* in_sizes, int n_in,
                              void* d_out, int out_size, void* d_ws, size_t ws_size,
                              hipStream_t stream) {
    const float* x  = (const float*)d_in[0];
    const float* ow = (const float*)d_in[1];
    const float* ob = (const float*)d_in[2];
    const float* mw = (const float*)d_in[3];
    const float* mb = (const float*)d_in[4];
    const float* dw = (const float*)d_in[5];
    float* out = (float*)d_out;

    unsigned short* wTm  = (unsigned short*)d_ws;          // 9*128*64
    unsigned short* wT27 = wTm + 9 * 128 * 64;             // 9*32*64

    hipLaunchKernelGGL(k_prep, dim3(360), dim3(256), 0, stream,
                       dw, ow, mw, wTm, wT27);
    hipLaunchKernelGGL(k_fused, dim3(Bc * NPB), dim3(256), 0, stream,
                       x, ob, mb, wTm, wT27, out);
}

// Round 3
// 148.835 us; speedup vs baseline: 1.7461x; 1.2351x over previous
//
#include <hip/hip_runtime.h>
#include <math.h>

#define Bc 4
#define Cc 64
#define Hh 96
#define Ww 96
#define Oo 128
#define HW 9216          // Hh*Ww
#define PT 32            // positions per block (one row segment)
#define NPB 288          // position tiles per image
#define RW 34            // staged region width  (cols wo0-1 .. wo0+32)
#define RS 72            // region/v col stride in bf16 elems (144 B, 16B aligned)

typedef __attribute__((ext_vector_type(8))) short bf16x8;
typedef __attribute__((ext_vector_type(4))) float f32x4;
typedef float f2u __attribute__((ext_vector_type(2), aligned(4)));  // unaligned-safe pair

__device__ inline unsigned short f2bf(float f) {
    unsigned u = __builtin_bit_cast(unsigned, f);
    return (unsigned short)((u + 0x7FFF + ((u >> 16) & 1)) >> 16);  // RNE
}

// ---------------------------------------------------------------------------
// Prep: transpose + bf16-cast weights.
//   wTm[k][oc][c]  (9 x 128 x 64)
//   wT27[k][ch][c] (9 x 32 x 64) ch 0..17 offset w, 18..26 mod w, rest 0
// ---------------------------------------------------------------------------
__global__ __launch_bounds__(256) void k_prep(
    const float* __restrict__ dw, const float* __restrict__ ow,
    const float* __restrict__ mw, unsigned short* __restrict__ wTm,
    unsigned short* __restrict__ wT27)
{
    int i = blockIdx.x * 256 + threadIdx.x;
    if (i < 9 * 128 * 64) {
        int c = i & 63, oc = (i >> 6) & 127, k = i >> 13;
        wTm[i] = f2bf(dw[(oc * 64 + c) * 9 + k]);
    }
    int j = i - 9 * 128 * 64;
    if (j >= 0 && j < 9 * 32 * 64) {
        int c = j & 63, ch = (j >> 6) & 31, k = j >> 11;
        float v = 0.f;
        if (ch < 18)      v = ow[(ch * 64 + c) * 9 + k];
        else if (ch < 27) v = mw[((ch - 18) * 64 + c) * 9 + k];
        wT27[j] = f2bf(v);
    }
}

// ---------------------------------------------------------------------------
// Fused: region-staged offset/mask conv (MFMA) -> sigmoid -> pipelined
// bilinear sampling -> main deform GEMM (MFMA).
// ---------------------------------------------------------------------------
__global__ __launch_bounds__(256, 4) void k_fused(
    const float* __restrict__ x, const float* __restrict__ ob,
    const float* __restrict__ mb, const unsigned short* __restrict__ wTm,
    const unsigned short* __restrict__ wT27, float* __restrict__ out)
{
    __shared__ short xreg[3 * RW * RS];      // 14688 B; reused as v dbl-buf (2*32*RS)
    __shared__ float offm_s[27 * 33];
    __shared__ float s_pw[9][4][PT];         // corner weights (mask folded)
    __shared__ int   s_pb[9][2][PT];         // row-pair base indices
    __shared__ int   s_ps[9][PT];            // sel0 | sel1<<1

    const int t = threadIdx.x;
    const int lid = (blockIdx.x & 7) * 144 + (blockIdx.x >> 3);  // XCD-contig tiles
    const int bb = lid / NPB;
    const int tile = lid - bb * NPB;
    const int ptile = tile * PT;
    const int ho = ptile / Ww;               // all 32 positions share this row
    const int wo0 = ptile - ho * Ww;
    const int wv = t >> 6;
    const int l = t & 63;
    const int lr = l & 15;
    const int quad = l >> 4;

    const float* xb = x + (size_t)bb * Cc * HW;

    // ---- stage x region: rows ho-1..ho+1, cols wo0-1..wo0+32, layout [r][col][c]
    for (int i = t; i < 3 * Cc * RW; i += 256) {
        int col = i % RW;
        int rc = i / RW;                     // r*64 + c
        int c = rc & 63;
        int r = rc >> 6;
        int h = ho + r - 1, w = wo0 + col - 1;
        float v = 0.f;
        if ((unsigned)h < (unsigned)Hh && (unsigned)w < (unsigned)Ww)
            v = xb[c * HW + h * Ww + w];
        xreg[(r * RW + col) * RS + c] = (short)f2bf(v);
    }
    __syncthreads();

    // ---- phase 1: 3x3 conv 64->27 via MFMA; A from region LDS, B from global
    f32x4 acc_o = {0.f, 0.f, 0.f, 0.f};
    const int mt1 = wv & 1;                  // pos half
    const int nt1 = wv >> 1;                 // ch half
#pragma unroll
    for (int k9 = 0; k9 < 9; ++k9) {
        const int di = k9 / 3, dj = k9 % 3;  // region-relative offsets
        const short* ar = &xreg[(di * RW + mt1 * 16 + lr + dj) * RS + quad * 8];
        const unsigned short* bg = wT27 + k9 * 2048 + (nt1 * 16 + lr) * 64 + quad * 8;
        bf16x8 a0 = *(const bf16x8*)(ar);
        bf16x8 a1 = *(const bf16x8*)(ar + 32);
        bf16x8 b0 = *(const bf16x8*)(bg);
        bf16x8 b1 = *(const bf16x8*)(bg + 32);
        acc_o = __builtin_amdgcn_mfma_f32_16x16x32_bf16(a0, b0, acc_o, 0, 0, 0);
        acc_o = __builtin_amdgcn_mfma_f32_16x16x32_bf16(a1, b1, acc_o, 0, 0, 0);
    }
    __syncthreads();                         // region reads done (xreg reusable later)
    {
        int ch = nt1 * 16 + lr;
        if (ch < 27) {
#pragma unroll
            for (int r = 0; r < 4; ++r)
                offm_s[ch * 33 + mt1 * 16 + quad * 4 + r] = acc_o[r];
        }
    }
    __syncthreads();

    // ---- phase 2: bias + 2*sigmoid, then all-tap bilinear params
    for (int i = t; i < 27 * PT; i += 256) {
        int ch = i >> 5, pos = i & 31;
        float v = offm_s[ch * 33 + pos];
        if (ch < 18) v += ob[ch];
        else         v = 2.f / (1.f + expf(-(v + mb[ch - 18])));
        offm_s[ch * 33 + pos] = v;
    }
    __syncthreads();
    for (int i = t; i < 9 * PT; i += 256) {
        int kk = i >> 5, pos = i & 31;
        float dy = offm_s[(2 * kk) * 33 + pos];
        float dx = offm_s[(2 * kk + 1) * 33 + pos];
        float mm = offm_s[(18 + kk) * 33 + pos];
        float py = (float)(ho - 1 + kk / 3) + dy;
        float px = (float)(wo0 + pos - 1 + kk % 3) + dx;
        float fy = floorf(py), fx = floorf(px);
        float ly = py - fy, lx = px - fx;
        int y0 = (int)fy, x0 = (int)fx;
        int y1 = y0 + 1, x1 = x0 + 1;
        float v00 = ((unsigned)y0 < (unsigned)Hh && (unsigned)x0 < (unsigned)Ww) ? 1.f : 0.f;
        float v01 = ((unsigned)y0 < (unsigned)Hh && (unsigned)x1 < (unsigned)Ww) ? 1.f : 0.f;
        float v10 = ((unsigned)y1 < (unsigned)Hh && (unsigned)x0 < (unsigned)Ww) ? 1.f : 0.f;
        float v11 = ((unsigned)y1 < (unsigned)Hh && (unsigned)x1 < (unsigned)Ww) ? 1.f : 0.f;
        int cy0 = min(max(y0, 0), Hh - 1), cy1 = min(max(y1, 0), Hh - 1);
        int cx0 = min(max(x0, 0), Ww - 1), cx1 = min(max(x1, 0), Ww - 1);
        int bcol = min(max(x0, 0), Ww - 2);
        s_pw[kk][0][pos] = (1.f - ly) * (1.f - lx) * mm * v00;
        s_pw[kk][1][pos] = (1.f - ly) * lx * mm * v01;
        s_pw[kk][2][pos] = ly * (1.f - lx) * mm * v10;
        s_pw[kk][3][pos] = ly * lx * mm * v11;
        s_pb[kk][0][pos] = cy0 * Ww + bcol;
        s_pb[kk][1][pos] = cy1 * Ww + bcol;
        s_ps[kk][pos] = (cx0 - bcol) | ((cx1 - bcol) << 1);
    }
    __syncthreads();

    // ---- phase 3: pipelined sampling + main GEMM
    const int pos = t & 31, cg = t >> 5;     // sampler mapping: 8 channels each
    const float* sbase = xb + (size_t)cg * 8 * HW;

    f32x4 accm[2][2];
#pragma unroll
    for (int mi = 0; mi < 2; ++mi)
#pragma unroll
        for (int ni = 0; ni < 2; ++ni)
            accm[mi][ni] = (f32x4){0.f, 0.f, 0.f, 0.f};

    // prologue: sample tap 0 into buffer 0
    {
        float w00 = s_pw[0][0][pos], w01 = s_pw[0][1][pos];
        float w10 = s_pw[0][2][pos], w11 = s_pw[0][3][pos];
        int rb0 = s_pb[0][0][pos], rb1 = s_pb[0][1][pos];
        int sp = s_ps[0][pos];
        bool s0 = sp & 1, s1 = sp & 2;
        f2u p0[8], p1[8];
#pragma unroll
        for (int c = 0; c < 8; ++c) {
            p0[c] = *(const f2u*)(sbase + c * HW + rb0);
            p1[c] = *(const f2u*)(sbase + c * HW + rb1);
        }
        union { bf16x8 v8; unsigned short us[8]; } u;
#pragma unroll
        for (int c = 0; c < 8; ++c) {
            float tl = s0 ? p0[c].y : p0[c].x;
            float tr = s1 ? p0[c].y : p0[c].x;
            float bl = s0 ? p1[c].y : p1[c].x;
            float br = s1 ? p1[c].y : p1[c].x;
            u.us[c] = f2bf(w00 * tl + w01 * tr + w10 * bl + w11 * br);
        }
        *(bf16x8*)&xreg[pos * RS + cg * 8] = u.v8;
    }
    __syncthreads();

    for (int k9 = 0; k9 < 9; ++k9) {
        // weight fragments for this tap (global, L2-hot) — issued first
        const unsigned short* wg = wTm + k9 * 8192 + (wv * 32 + lr) * 64 + quad * 8;
        bf16x8 wa00 = *(const bf16x8*)(wg);
        bf16x8 wa01 = *(const bf16x8*)(wg + 32);
        bf16x8 wa10 = *(const bf16x8*)(wg + 16 * 64);
        bf16x8 wa11 = *(const bf16x8*)(wg + 16 * 64 + 32);

        // issue next tap's gathers (stay in flight through the MFMAs)
        f2u p0[8], p1[8];
        float w00 = 0.f, w01 = 0.f, w10 = 0.f, w11 = 0.f;
        bool s0 = false, s1 = false;
        if (k9 < 8) {
            int kk = k9 + 1;
            w00 = s_pw[kk][0][pos]; w01 = s_pw[kk][1][pos];
            w10 = s_pw[kk][2][pos]; w11 = s_pw[kk][3][pos];
            int rb0 = s_pb[kk][0][pos], rb1 = s_pb[kk][1][pos];
            int sp = s_ps[kk][pos];
            s0 = sp & 1; s1 = sp & 2;
#pragma unroll
            for (int c = 0; c < 8; ++c) {
                p0[c] = *(const f2u*)(sbase + c * HW + rb0);
                p1[c] = *(const f2u*)(sbase + c * HW + rb1);
            }
        }

        // MFMA on current buffer
        const short* cur = &xreg[(k9 & 1) * 32 * RS];
#pragma unroll
        for (int ks = 0; ks < 64; ks += 32) {
            bf16x8 b0 = *(const bf16x8*)&cur[lr * RS + quad * 8 + ks];
            bf16x8 b1 = *(const bf16x8*)&cur[(16 + lr) * RS + quad * 8 + ks];
            bf16x8 a0 = (ks == 0) ? wa00 : wa01;
            bf16x8 a1 = (ks == 0) ? wa10 : wa11;
            accm[0][0] = __builtin_amdgcn_mfma_f32_16x16x32_bf16(a0, b0, accm[0][0], 0, 0, 0);
            accm[0][1] = __builtin_amdgcn_mfma_f32_16x16x32_bf16(a0, b1, accm[0][1], 0, 0, 0);
            accm[1][0] = __builtin_amdgcn_mfma_f32_16x16x32_bf16(a1, b0, accm[1][0], 0, 0, 0);
            accm[1][1] = __builtin_amdgcn_mfma_f32_16x16x32_bf16(a1, b1, accm[1][1], 0, 0, 0);
        }

        // convert + store next tap into the other buffer
        if (k9 < 8) {
            union { bf16x8 v8; unsigned short us[8]; } u;
#pragma unroll
            for (int c = 0; c < 8; ++c) {
                float tl = s0 ? p0[c].y : p0[c].x;
                float tr = s1 ? p0[c].y : p0[c].x;
                float bl = s0 ? p1[c].y : p1[c].x;
                float br = s1 ? p1[c].y : p1[c].x;
                u.us[c] = f2bf(w00 * tl + w01 * tr + w10 * bl + w11 * br);
            }
            *(bf16x8*)&xreg[((k9 + 1) & 1) * 32 * RS + pos * RS + cg * 8] = u.v8;
        }
        __syncthreads();
    }

    // ---- epilogue: out[b][oc][ptile + pos]
    float* outp = out + (size_t)bb * Oo * HW + ptile;
#pragma unroll
    for (int mi = 0; mi < 2; ++mi) {
#pragma unroll
        for (int r = 0; r < 4; ++r) {
            int oc = (2 * wv + mi) * 16 + quad * 4 + r;
#pragma unroll
            for (int ni = 0; ni < 2; ++ni)
                outp[(size_t)oc * HW + ni * 16 + lr] = accm[mi][ni][r];
        }
    }
}

extern "C" void kernel_launch(void* const* d_in, const int* in_sizes, int n_in,
                              void* d_out, int out_size, void* d_ws, size_t ws_size,
                              hipStream_t stream) {
    const float* x  = (const float*)d_in[0];
    const float* ow = (const float*)d_in[1];
    const float* ob = (const float*)d_in[2];
    const float* mw = (const float*)d_in[3];
    const float* mb = (const float*)d_in[4];
    const float* dw = (const float*)d_in[5];
    float* out = (float*)d_out;

    unsigned short* wTm  = (unsigned short*)d_ws;          // 9*128*64
    unsigned short* wT27 = wTm + 9 * 128 * 64;             // 9*32*64

    hipLaunchKernelGGL(k_prep, dim3(360), dim3(256), 0, stream,
                       dw, ow, mw, wTm, wT27);
    hipLaunchKernelGGL(k_fused, dim3(Bc * NPB), dim3(256), 0, stream,
                       x, ob, mb, wTm, wT27, out);
}

// Round 4
// 143.030 us; speedup vs baseline: 1.8169x; 1.0406x over previous
//
#include <hip/hip_runtime.h>
#include <math.h>

#define Bc 4
#define Cc 64
#define Hh 96
#define Ww 96
#define Oo 128
#define HW 9216          // Hh*Ww
#define PT 32            // positions per k_off block
#define NPB 288          // 32-pos tiles per image
#define NP16 576         // 16-pos tiles per image
#define RW 34            // staged region width
#define RS 72            // region col stride (bf16), 144 B

typedef __attribute__((ext_vector_type(8))) short bf16x8;
typedef __attribute__((ext_vector_type(4))) float f32x4;
typedef float f2u __attribute__((ext_vector_type(2), aligned(4)));

__device__ inline unsigned short f2bf(float f) {
    unsigned u = __builtin_bit_cast(unsigned, f);
    return (unsigned short)((u + 0x7FFF + ((u >> 16) & 1)) >> 16);  // RNE
}

// ---------------------------------------------------------------------------
// Prep: pack weights into MFMA fragment layouts (lane-major, coalesced loads).
//  wTmF: A-frags of main W. frag-block fb = k*16 + m*2 + s  (m=oc/16, s=K-step)
//        elem [l][j] = W[oc = m*16 + (l&15)][c = s*32 + (l>>4)*8 + j]
//  w27F: B-frags of offset/mod W. fb2 = (k*2+s)*2 + nt
//        elem [l][j] = W27[ch = nt*16 + (l&15)][c = s*32 + (l>>4)*8 + j]
// ---------------------------------------------------------------------------
__global__ __launch_bounds__(256) void k_prep(
    const float* __restrict__ dw, const float* __restrict__ ow,
    const float* __restrict__ mw, unsigned short* __restrict__ wTmF,
    unsigned short* __restrict__ w27F)
{
    int i = blockIdx.x * 256 + threadIdx.x;
    if (i < 9 * 8 * 2 * 512) {
        int j = i & 7, l = (i >> 3) & 63, fb = i >> 9;
        int s = fb & 1, m = (fb >> 1) & 7, k = fb >> 4;
        int oc = m * 16 + (l & 15);
        int c = s * 32 + (l >> 4) * 8 + j;
        wTmF[i] = f2bf(dw[(oc * 64 + c) * 9 + k]);
    }
    int jj = i - 9 * 8 * 2 * 512;
    if (jj >= 0 && jj < 9 * 2 * 2 * 512) {
        int j = jj & 7, l = (jj >> 3) & 63, fb2 = jj >> 9;
        int nt = fb2 & 1, s = (fb2 >> 1) & 1, k = fb2 >> 2;
        int ch = nt * 16 + (l & 15);
        int c = s * 32 + (l >> 4) * 8 + j;
        float v = 0.f;
        if (ch < 18)      v = ow[(ch * 64 + c) * 9 + k];
        else if (ch < 27) v = mw[((ch - 18) * 64 + c) * 9 + k];
        w27F[jj] = f2bf(v);
    }
}

// ---------------------------------------------------------------------------
// k_off: offset/mask conv (MFMA) -> sigmoid -> bilinear params -> BARRIER-FREE
// sampling tail writing v in B-fragment layout:
//   vF[b][k][p16][ks][lane][8],  lane = quad*16 + posin16,
//   elem = v[pos = p16*16 + posin16][c = ks*32 + quad*8 + j]
// ---------------------------------------------------------------------------
__global__ __launch_bounds__(256, 2) void k_off(
    const float* __restrict__ x, const float* __restrict__ ob,
    const float* __restrict__ mb, const unsigned short* __restrict__ w27F,
    unsigned short* __restrict__ vF)
{
    __shared__ short xreg[3 * RW * RS];
    __shared__ float offm_s[27 * 33];
    __shared__ float s_pw[9][4][PT];
    __shared__ int   s_pb[9][2][PT];
    __shared__ int   s_ps[9][PT];

    const int t = threadIdx.x;
    const int lid = (blockIdx.x & 7) * 144 + (blockIdx.x >> 3);
    const int bb = lid / NPB;
    const int tile = lid - bb * NPB;
    const int ho = tile / 3;
    const int wo0 = (tile - ho * 3) * 32;
    const int wv = t >> 6;
    const int l = t & 63;
    const int lr = l & 15;
    const int quad = l >> 4;

    const float* xb = x + (size_t)bb * Cc * HW;

    // region stage: rows ho-1..ho+1, cols wo0-1..wo0+32
    for (int i = t; i < 3 * Cc * RW; i += 256) {
        int col = i % RW;
        int rc = i / RW;
        int c = rc & 63, r = rc >> 6;
        int h = ho + r - 1, w = wo0 + col - 1;
        float v = 0.f;
        if ((unsigned)h < (unsigned)Hh && (unsigned)w < (unsigned)Ww)
            v = xb[c * HW + h * Ww + w];
        xreg[(r * RW + col) * RS + c] = (short)f2bf(v);
    }
    __syncthreads();

    // phase 1: conv 64->27 via MFMA, B-frags coalesced from w27F
    f32x4 acc_o = {0.f, 0.f, 0.f, 0.f};
    const int mt1 = wv & 1;
    const int nt1 = wv >> 1;
#pragma unroll
    for (int k9 = 0; k9 < 9; ++k9) {
        const int di = k9 / 3, dj = k9 % 3;
        const short* ar = &xreg[(di * RW + mt1 * 16 + lr + dj) * RS + quad * 8];
#pragma unroll
        for (int s = 0; s < 2; ++s) {
            bf16x8 a = *(const bf16x8*)(ar + s * 32);
            bf16x8 b = *(const bf16x8*)(w27F + (((k9 * 2 + s) * 2 + nt1) << 9) + l * 8);
            acc_o = __builtin_amdgcn_mfma_f32_16x16x32_bf16(a, b, acc_o, 0, 0, 0);
        }
    }
    __syncthreads();
    {
        int ch = nt1 * 16 + lr;
        if (ch < 27) {
#pragma unroll
            for (int r = 0; r < 4; ++r)
                offm_s[ch * 33 + mt1 * 16 + quad * 4 + r] = acc_o[r];
        }
    }
    __syncthreads();

    // phase 2: bias + 2*sigmoid, then bilinear params for all taps
    for (int i = t; i < 27 * PT; i += 256) {
        int ch = i >> 5, pos = i & 31;
        float v = offm_s[ch * 33 + pos];
        if (ch < 18) v += ob[ch];
        else         v = 2.f / (1.f + expf(-(v + mb[ch - 18])));
        offm_s[ch * 33 + pos] = v;
    }
    __syncthreads();
    for (int i = t; i < 9 * PT; i += 256) {
        int kk = i >> 5, pos = i & 31;
        float dy = offm_s[(2 * kk) * 33 + pos];
        float dx = offm_s[(2 * kk + 1) * 33 + pos];
        float mm = offm_s[(18 + kk) * 33 + pos];
        float py = (float)(ho - 1 + kk / 3) + dy;
        float px = (float)(wo0 + pos - 1 + kk % 3) + dx;
        float fy = floorf(py), fx = floorf(px);
        float ly = py - fy, lx = px - fx;
        int y0 = (int)fy, x0 = (int)fx;
        int y1 = y0 + 1, x1 = x0 + 1;
        float v00 = ((unsigned)y0 < (unsigned)Hh && (unsigned)x0 < (unsigned)Ww) ? 1.f : 0.f;
        float v01 = ((unsigned)y0 < (unsigned)Hh && (unsigned)x1 < (unsigned)Ww) ? 1.f : 0.f;
        float v10 = ((unsigned)y1 < (unsigned)Hh && (unsigned)x0 < (unsigned)Ww) ? 1.f : 0.f;
        float v11 = ((unsigned)y1 < (unsigned)Hh && (unsigned)x1 < (unsigned)Ww) ? 1.f : 0.f;
        int cy0 = min(max(y0, 0), Hh - 1), cy1 = min(max(y1, 0), Hh - 1);
        int cx0 = min(max(x0, 0), Ww - 1), cx1 = min(max(x1, 0), Ww - 1);
        int bcol = min(max(x0, 0), Ww - 2);
        s_pw[kk][0][pos] = (1.f - ly) * (1.f - lx) * mm * v00;
        s_pw[kk][1][pos] = (1.f - ly) * lx * mm * v01;
        s_pw[kk][2][pos] = ly * (1.f - lx) * mm * v10;
        s_pw[kk][3][pos] = ly * lx * mm * v11;
        s_pb[kk][0][pos] = cy0 * Ww + bcol;
        s_pb[kk][1][pos] = cy1 * Ww + bcol;
        s_ps[kk][pos] = (cx0 - bcol) | ((cx1 - bcol) << 1);
    }
    __syncthreads();

    // phase 3: barrier-free sampling tail -> vF (B-fragment layout)
    const int pos = t & 31, cg = t >> 5;
    const int ks = cg >> 2, quad4 = cg & 3;
    const float* sbase = xb + (size_t)cg * 8 * HW;
    unsigned short* vbase = vF
        + ((((size_t)bb * 9) * NP16 + (tile * 2 + (pos >> 4))) * 2 + ks) * 512
        + (quad4 * 16 + (pos & 15)) * 8;
    const size_t vstep = (size_t)NP16 * 2 * 512;   // per tap

    for (int k9 = 0; k9 < 9; ++k9) {
        float w00 = s_pw[k9][0][pos], w01 = s_pw[k9][1][pos];
        float w10 = s_pw[k9][2][pos], w11 = s_pw[k9][3][pos];
        int rb0 = s_pb[k9][0][pos], rb1 = s_pb[k9][1][pos];
        int sp = s_ps[k9][pos];
        bool s0 = sp & 1, s1 = sp & 2;
        f2u p0[8], p1[8];
#pragma unroll
        for (int c = 0; c < 8; ++c) {
            p0[c] = *(const f2u*)(sbase + c * HW + rb0);
            p1[c] = *(const f2u*)(sbase + c * HW + rb1);
        }
        union { bf16x8 v8; unsigned short us[8]; } u;
#pragma unroll
        for (int c = 0; c < 8; ++c) {
            float tl = s0 ? p0[c].y : p0[c].x;
            float tr = s1 ? p0[c].y : p0[c].x;
            float bl = s0 ? p1[c].y : p1[c].x;
            float br = s1 ? p1[c].y : p1[c].x;
            u.us[c] = f2bf(w00 * tl + w01 * tr + w10 * bl + w11 * br);
        }
        *(bf16x8*)(vbase + k9 * vstep) = u.v8;
    }
}

// ---------------------------------------------------------------------------
// k_gemm: C[oc][pos] = sum_k W_k · V_k. Pure register MFMA GEMM:
// no LDS, no barriers; every A/B fragment is one coalesced b128 global load.
// Block = 128 threads: wave mt=0/1 covers 64 oc x 32 pos.
// ---------------------------------------------------------------------------
__global__ __launch_bounds__(128, 2) void k_gemm(
    const unsigned short* __restrict__ wTmF,
    const unsigned short* __restrict__ vF, float* __restrict__ out)
{
    const int t = threadIdx.x;
    const int l = t & 63;
    const int mt = t >> 6;                       // oc half
    const int bid = blockIdx.x;                  // 0..1151
    const int bb = bid / NPB;
    const int tile = bid - bb * NPB;             // 32-pos tile
    const int lr = l & 15, quad = l >> 4;

    f32x4 acc[4][2];
#pragma unroll
    for (int m = 0; m < 4; ++m)
#pragma unroll
        for (int nn = 0; nn < 2; ++nn)
            acc[m][nn] = (f32x4){0.f, 0.f, 0.f, 0.f};

    const size_t vtap = (size_t)NP16 * 2 * 512;
    const unsigned short* vb =
        vF + ((size_t)bb * 9 * NP16 + tile * 2) * 2 * 512 + l * 8;
    const unsigned short* wb = wTmF + (mt * 4) * 2 * 512 + l * 8;

    for (int k9 = 0; k9 < 9; ++k9) {
        bf16x8 Bf[2][2], Af[4][2];
#pragma unroll
        for (int nn = 0; nn < 2; ++nn)
#pragma unroll
            for (int s = 0; s < 2; ++s)
                Bf[nn][s] = *(const bf16x8*)(vb + k9 * vtap + (nn * 2 + s) * 512);
#pragma unroll
        for (int m = 0; m < 4; ++m)
#pragma unroll
            for (int s = 0; s < 2; ++s)
                Af[m][s] = *(const bf16x8*)(wb + (size_t)(k9 * 16 + m * 2 + s) * 512);
#pragma unroll
        for (int m = 0; m < 4; ++m)
#pragma unroll
            for (int nn = 0; nn < 2; ++nn)
#pragma unroll
                for (int s = 0; s < 2; ++s)
                    acc[m][nn] = __builtin_amdgcn_mfma_f32_16x16x32_bf16(
                        Af[m][s], Bf[nn][s], acc[m][nn], 0, 0, 0);
    }

    float* outp = out + (size_t)bb * Oo * HW + tile * PT;
#pragma unroll
    for (int m = 0; m < 4; ++m) {
#pragma unroll
        for (int r = 0; r < 4; ++r) {
            int oc = mt * 64 + m * 16 + quad * 4 + r;
#pragma unroll
            for (int nn = 0; nn < 2; ++nn)
                outp[(size_t)oc * HW + nn * 16 + lr] = acc[m][nn][r];
        }
    }
}

extern "C" void kernel_launch(void* const* d_in, const int* in_sizes, int n_in,
                              void* d_out, int out_size, void* d_ws, size_t ws_size,
                              hipStream_t stream) {
    const float* x  = (const float*)d_in[0];
    const float* ow = (const float*)d_in[1];
    const float* ob = (const float*)d_in[2];
    const float* mw = (const float*)d_in[3];
    const float* mb = (const float*)d_in[4];
    const float* dw = (const float*)d_in[5];
    float* out = (float*)d_out;

    unsigned short* wTmF = (unsigned short*)d_ws;          // 73728 shorts
    unsigned short* w27F = wTmF + 9 * 8 * 2 * 512;         // 18432 shorts
    unsigned short* vF   = w27F + 9 * 2 * 2 * 512;         // 4*9*576*2*512 shorts

    hipLaunchKernelGGL(k_prep, dim3(360), dim3(256), 0, stream,
                       dw, ow, mw, wTmF, w27F);
    hipLaunchKernelGGL(k_off, dim3(Bc * NPB), dim3(256), 0, stream,
                       x, ob, mb, w27F, vF);
    hipLaunchKernelGGL(k_gemm, dim3(Bc * NPB), dim3(128), 0, stream,
                       wTmF, vF, out);
}

// Round 5
// 125.162 us; speedup vs baseline: 2.0763x; 1.1428x over previous
//
#include <hip/hip_runtime.h>
#include <math.h>

#define Bc 4
#define Cc 64
#define Hh 96
#define Ww 96
#define Oo 128
#define HW 9216          // Hh*Ww
#define PT 32            // positions per k_off block
#define NPB 288          // 32-pos tiles per image
#define NP16 576         // 16-pos tiles per image
#define RW 34            // staged region width
#define RS 72            // region col stride (bf16), 144 B (16B-aligned rows)

typedef __attribute__((ext_vector_type(8))) short bf16x8;
typedef __attribute__((ext_vector_type(4))) float f32x4;

__device__ inline unsigned short f2bf(float f) {
    unsigned u = __builtin_bit_cast(unsigned, f);
    return (unsigned short)((u + 0x7FFF + ((u >> 16) & 1)) >> 16);  // RNE
}
__device__ inline float bf2f(short s) {
    return __builtin_bit_cast(float, ((unsigned)(unsigned short)s) << 16);
}

// ---------------------------------------------------------------------------
// Prep: pack weights into MFMA fragment layouts (lane-major, coalesced).
//  wTmF: A-frags of main W. fb = k*16 + m*2 + s ; elem[l][j] =
//        W[oc = m*16 + (l&15)][c = s*32 + (l>>4)*8 + j]
//  w27F: B-frags of offset/mod W. fb2 = (k*2+s)*2 + nt
// ---------------------------------------------------------------------------
__global__ __launch_bounds__(256) void k_prep(
    const float* __restrict__ dw, const float* __restrict__ ow,
    const float* __restrict__ mw, unsigned short* __restrict__ wTmF,
    unsigned short* __restrict__ w27F)
{
    int i = blockIdx.x * 256 + threadIdx.x;
    if (i < 9 * 8 * 2 * 512) {
        int j = i & 7, l = (i >> 3) & 63, fb = i >> 9;
        int s = fb & 1, m = (fb >> 1) & 7, k = fb >> 4;
        int oc = m * 16 + (l & 15);
        int c = s * 32 + (l >> 4) * 8 + j;
        wTmF[i] = f2bf(dw[(oc * 64 + c) * 9 + k]);
    }
    int jj = i - 9 * 8 * 2 * 512;
    if (jj >= 0 && jj < 9 * 2 * 2 * 512) {
        int j = jj & 7, l = (jj >> 3) & 63, fb2 = jj >> 9;
        int nt = fb2 & 1, s = (fb2 >> 1) & 1, k = fb2 >> 2;
        int ch = nt * 16 + (l & 15);
        int c = s * 32 + (l >> 4) * 8 + j;
        float v = 0.f;
        if (ch < 18)      v = ow[(ch * 64 + c) * 9 + k];
        else if (ch < 27) v = mw[((ch - 18) * 64 + c) * 9 + k];
        w27F[jj] = f2bf(v);
    }
}

// ---------------------------------------------------------------------------
// k_xT: x [b][c][h][w] fp32 -> xT [b][h][w][c] bf16 (channels-last).
// 576 blocks x 64 thr; thread owns one position, 64 coalesced loads,
// 8 b128 stores. XCD swizzle matches k_off's half-image ownership.
// ---------------------------------------------------------------------------
__global__ __launch_bounds__(64) void k_xT(const float* __restrict__ x,
                                           unsigned short* __restrict__ xT)
{
    const int bid = blockIdx.x;
    const int gc = (bid & 7) * 72 + (bid >> 3);      // 0..575
    const int b = gc / 144;
    const int p0 = (gc - b * 144) * 64;
    const int t = threadIdx.x;
    const float* xb = x + (size_t)b * Cc * HW + p0 + t;
    unsigned short* ob = xT + ((size_t)b * HW + p0 + t) * 64;
#pragma unroll
    for (int q = 0; q < 8; ++q) {
        union { bf16x8 v8; unsigned short us[8]; } u;
#pragma unroll
        for (int c = 0; c < 8; ++c)
            u.us[c] = f2bf(xb[(size_t)(q * 8 + c) * HW]);
        *(bf16x8*)(ob + q * 8) = u.v8;
    }
}

// ---------------------------------------------------------------------------
// k_off: offset/mask conv (MFMA) -> sigmoid -> params -> barrier-free
// sampling from channels-last xT (1 b128 per corner), 2-tap pipeline,
// writes vF in B-fragment layout (same as R4).
// ---------------------------------------------------------------------------
__global__ __launch_bounds__(256, 4) void k_off(
    const unsigned short* __restrict__ xT, const float* __restrict__ ob,
    const float* __restrict__ mb, const unsigned short* __restrict__ w27F,
    unsigned short* __restrict__ vF)
{
    __shared__ short xreg[3 * RW * RS];
    __shared__ float offm_s[27 * 33];
    __shared__ float s_pw[9][4][PT];     // corner weights (validity+mask folded)
    __shared__ int   s_pi[9][4][PT];     // corner base offsets (*64, channels-last)

    const int t = threadIdx.x;
    const int lid = (blockIdx.x & 7) * 144 + (blockIdx.x >> 3);
    const int bb = lid / NPB;
    const int tile = lid - bb * NPB;
    const int ho = tile / 3;
    const int wo0 = (tile - ho * 3) * 32;
    const int wv = t >> 6;
    const int l = t & 63;
    const int lr = l & 15;
    const int quad = l >> 4;

    const unsigned short* xTb = xT + (size_t)bb * HW * 64;

    // region stage from xT: rows ho-1..ho+1, cols wo0-1..wo0+32 (b128 copies)
    static const bf16x8 zero8 = {0, 0, 0, 0, 0, 0, 0, 0};
    for (int i = t; i < 3 * RW * 8; i += 256) {
        int q = i & 7;
        int rc = i >> 3;
        int col = rc % RW, r = rc / RW;
        int h = ho + r - 1, w = wo0 + col - 1;
        bf16x8 val = zero8;
        if ((unsigned)h < (unsigned)Hh && (unsigned)w < (unsigned)Ww)
            val = *(const bf16x8*)(xTb + ((size_t)(h * Ww + w)) * 64 + q * 8);
        *(bf16x8*)&xreg[(r * RW + col) * RS + q * 8] = val;
    }
    __syncthreads();

    // phase 1: conv 64->27 via MFMA (A from region LDS, B coalesced global)
    f32x4 acc_o = {0.f, 0.f, 0.f, 0.f};
    const int mt1 = wv & 1;
    const int nt1 = wv >> 1;
#pragma unroll
    for (int k9 = 0; k9 < 9; ++k9) {
        const int di = k9 / 3, dj = k9 % 3;
        const short* ar = &xreg[(di * RW + mt1 * 16 + lr + dj) * RS + quad * 8];
#pragma unroll
        for (int s = 0; s < 2; ++s) {
            bf16x8 a = *(const bf16x8*)(ar + s * 32);
            bf16x8 b = *(const bf16x8*)(w27F + (((k9 * 2 + s) * 2 + nt1) << 9) + l * 8);
            acc_o = __builtin_amdgcn_mfma_f32_16x16x32_bf16(a, b, acc_o, 0, 0, 0);
        }
    }
    __syncthreads();
    {
        int ch = nt1 * 16 + lr;
        if (ch < 27) {
#pragma unroll
            for (int r = 0; r < 4; ++r)
                offm_s[ch * 33 + mt1 * 16 + quad * 4 + r] = acc_o[r];
        }
    }
    __syncthreads();

    // phase 2: bias + 2*sigmoid, then bilinear params for all 9 taps
    for (int i = t; i < 27 * PT; i += 256) {
        int ch = i >> 5, pos = i & 31;
        float v = offm_s[ch * 33 + pos];
        if (ch < 18) v += ob[ch];
        else         v = 2.f / (1.f + expf(-(v + mb[ch - 18])));
        offm_s[ch * 33 + pos] = v;
    }
    __syncthreads();
    for (int i = t; i < 9 * PT; i += 256) {
        int kk = i >> 5, pos = i & 31;
        float dy = offm_s[(2 * kk) * 33 + pos];
        float dx = offm_s[(2 * kk + 1) * 33 + pos];
        float mm = offm_s[(18 + kk) * 33 + pos];
        float py = (float)(ho - 1 + kk / 3) + dy;
        float px = (float)(wo0 + pos - 1 + kk % 3) + dx;
        float fy = floorf(py), fx = floorf(px);
        float ly = py - fy, lx = px - fx;
        int y0 = (int)fy, x0 = (int)fx;
        int y1 = y0 + 1, x1 = x0 + 1;
        float v00 = ((unsigned)y0 < (unsigned)Hh && (unsigned)x0 < (unsigned)Ww) ? 1.f : 0.f;
        float v01 = ((unsigned)y0 < (unsigned)Hh && (unsigned)x1 < (unsigned)Ww) ? 1.f : 0.f;
        float v10 = ((unsigned)y1 < (unsigned)Hh && (unsigned)x0 < (unsigned)Ww) ? 1.f : 0.f;
        float v11 = ((unsigned)y1 < (unsigned)Hh && (unsigned)x1 < (unsigned)Ww) ? 1.f : 0.f;
        int cy0 = min(max(y0, 0), Hh - 1), cy1 = min(max(y1, 0), Hh - 1);
        int cx0 = min(max(x0, 0), Ww - 1), cx1 = min(max(x1, 0), Ww - 1);
        s_pw[kk][0][pos] = (1.f - ly) * (1.f - lx) * mm * v00;
        s_pw[kk][1][pos] = (1.f - ly) * lx * mm * v01;
        s_pw[kk][2][pos] = ly * (1.f - lx) * mm * v10;
        s_pw[kk][3][pos] = ly * lx * mm * v11;
        s_pi[kk][0][pos] = (cy0 * Ww + cx0) * 64;
        s_pi[kk][1][pos] = (cy0 * Ww + cx1) * 64;
        s_pi[kk][2][pos] = (cy1 * Ww + cx0) * 64;
        s_pi[kk][3][pos] = (cy1 * Ww + cx1) * 64;
    }
    __syncthreads();

    // phase 3: barrier-free sampling -> vF (B-frag layout), 2-tap pipeline
    const int pos = t & 31, cg = t >> 5;
    const int cg8 = cg * 8;
    const int ks = cg >> 2, quad4 = cg & 3;
    unsigned short* vbase = vF
        + ((((size_t)bb * 9) * NP16 + (tile * 2 + (pos >> 4))) * 2 + ks) * 512
        + (quad4 * 16 + (pos & 15)) * 8;
    const size_t vstep = (size_t)NP16 * 2 * 512;   // per tap

    bf16x8 P0[4], P1[4];
#pragma unroll
    for (int cr = 0; cr < 4; ++cr)
        P0[cr] = *(const bf16x8*)(xTb + s_pi[0][cr][pos] + cg8);

#pragma unroll
    for (int k9 = 0; k9 < 9; ++k9) {
        bf16x8* cur = (k9 & 1) ? P1 : P0;
        bf16x8* nxt = (k9 & 1) ? P0 : P1;
        if (k9 < 8) {
#pragma unroll
            for (int cr = 0; cr < 4; ++cr)
                nxt[cr] = *(const bf16x8*)(xTb + s_pi[k9 + 1][cr][pos] + cg8);
        }
        float w00 = s_pw[k9][0][pos], w01 = s_pw[k9][1][pos];
        float w10 = s_pw[k9][2][pos], w11 = s_pw[k9][3][pos];
        union { bf16x8 v8; unsigned short us[8]; } o;
#pragma unroll
        for (int j = 0; j < 8; ++j) {
            float a0 = bf2f(cur[0][j]);
            float a1 = bf2f(cur[1][j]);
            float a2 = bf2f(cur[2][j]);
            float a3 = bf2f(cur[3][j]);
            o.us[j] = f2bf(w00 * a0 + w01 * a1 + w10 * a2 + w11 * a3);
        }
        *(bf16x8*)(vbase + k9 * vstep) = o.v8;
    }
}

// ---------------------------------------------------------------------------
// k_gemm: C[oc][pos] = sum_k W_k · V_k. Register MFMA GEMM, no LDS/barriers.
// 256 thr: wave wv covers oc [wv*32, wv*32+32) x all 32 pos. Double-buffered
// A/B frags across taps. XCD swizzle matches k_off so vF reads are local-L2.
// ---------------------------------------------------------------------------
__global__ __launch_bounds__(256, 4) void k_gemm(
    const unsigned short* __restrict__ wTmF,
    const unsigned short* __restrict__ vF, float* __restrict__ out)
{
    const int t = threadIdx.x;
    const int l = t & 63;
    const int wv = t >> 6;
    const int gt = (blockIdx.x & 7) * 144 + (blockIdx.x >> 3);
    const int bb = gt / NPB;
    const int tile = gt - bb * NPB;
    const int lr = l & 15, quad = l >> 4;

    f32x4 acc[2][2];
#pragma unroll
    for (int m = 0; m < 2; ++m)
#pragma unroll
        for (int nn = 0; nn < 2; ++nn)
            acc[m][nn] = (f32x4){0.f, 0.f, 0.f, 0.f};

    const size_t vtap = (size_t)NP16 * 2 * 512;
    const unsigned short* vb =
        vF + ((size_t)bb * 9 * NP16 + tile * 2) * 2 * 512 + l * 8;
    const unsigned short* wb = wTmF + l * 8;

    bf16x8 Af[2][2][2], Bf[2][2][2];   // [buf][x][s]
    auto loadtap = [&](int buf, int kk) {
#pragma unroll
        for (int mi = 0; mi < 2; ++mi)
#pragma unroll
            for (int s = 0; s < 2; ++s)
                Af[buf][mi][s] = *(const bf16x8*)(
                    wb + (size_t)((kk * 16 + (wv * 2 + mi) * 2 + s) << 9));
#pragma unroll
        for (int nn = 0; nn < 2; ++nn)
#pragma unroll
            for (int s = 0; s < 2; ++s)
                Bf[buf][nn][s] = *(const bf16x8*)(
                    vb + kk * vtap + (nn * 2 + s) * 512);
    };

    loadtap(0, 0);
#pragma unroll
    for (int k9 = 0; k9 < 9; ++k9) {
        const int cb = k9 & 1;
        if (k9 < 8) loadtap(cb ^ 1, k9 + 1);
#pragma unroll
        for (int m = 0; m < 2; ++m)
#pragma unroll
            for (int nn = 0; nn < 2; ++nn)
#pragma unroll
                for (int s = 0; s < 2; ++s)
                    acc[m][nn] = __builtin_amdgcn_mfma_f32_16x16x32_bf16(
                        Af[cb][m][s], Bf[cb][nn][s], acc[m][nn], 0, 0, 0);
    }

    float* outp = out + (size_t)bb * Oo * HW + tile * PT;
#pragma unroll
    for (int m = 0; m < 2; ++m) {
#pragma unroll
        for (int r = 0; r < 4; ++r) {
            int oc = wv * 32 + m * 16 + quad * 4 + r;
#pragma unroll
            for (int nn = 0; nn < 2; ++nn)
                outp[(size_t)oc * HW + nn * 16 + lr] = acc[m][nn][r];
        }
    }
}

extern "C" void kernel_launch(void* const* d_in, const int* in_sizes, int n_in,
                              void* d_out, int out_size, void* d_ws, size_t ws_size,
                              hipStream_t stream) {
    const float* x  = (const float*)d_in[0];
    const float* ow = (const float*)d_in[1];
    const float* ob = (const float*)d_in[2];
    const float* mw = (const float*)d_in[3];
    const float* mb = (const float*)d_in[4];
    const float* dw = (const float*)d_in[5];
    float* out = (float*)d_out;

    unsigned short* wTmF = (unsigned short*)d_ws;          // 73728
    unsigned short* w27F = wTmF + 9 * 8 * 2 * 512;         // 18432
    unsigned short* vF   = w27F + 9 * 2 * 2 * 512;         // 21233664
    unsigned short* xT   = vF + (size_t)Bc * 9 * NP16 * 2 * 512;  // 2359296

    hipLaunchKernelGGL(k_prep, dim3(360), dim3(256), 0, stream,
                       dw, ow, mw, wTmF, w27F);
    hipLaunchKernelGGL(k_xT, dim3(576), dim3(64), 0, stream, x, xT);
    hipLaunchKernelGGL(k_off, dim3(Bc * NPB), dim3(256), 0, stream,
                       xT, ob, mb, w27F, vF);
    hipLaunchKernelGGL(k_gemm, dim3(Bc * NPB), dim3(256), 0, stream,
                       wTmF, vF, out);
}